// Round 1
// baseline (162.963 us; speedup 1.0000x reference)
//
#include <hip/hip_runtime.h>

// Householder reflection per row: out = z - 2 * v * (v.z) / (v.v)
// B = 1048576 rows, L = 64 fp32 per row.
// Layout: 16 lanes per row, one float4 (16B) per lane -> fully coalesced.
// Dot products reduced across the 16-lane group via __shfl_xor.
__global__ void HF_28063316312693_kernel(const float* __restrict__ v,
                                         const float* __restrict__ z,
                                         float* __restrict__ out,
                                         int B) {
    const int tid = blockIdx.x * blockDim.x + threadIdx.x;
    const int nthreads = gridDim.x * blockDim.x;
    const int lane4 = tid & 15;            // float4 slot within the row (0..15)
    const int row_stride = nthreads >> 4;  // rows covered per grid sweep

    for (int row = tid >> 4; row < B; row += row_stride) {
        const size_t base = (size_t)row * 64;
        const float4 v4 = reinterpret_cast<const float4*>(v + base)[lane4];
        const float4 z4 = reinterpret_cast<const float4*>(z + base)[lane4];

        float vz = v4.x * z4.x + v4.y * z4.y + v4.z * z4.z + v4.w * z4.w;
        float nn = v4.x * v4.x + v4.y * v4.y + v4.z * v4.z + v4.w * v4.w;

        // Reduce across the 16-lane group (lane ^ {1,2,4,8} stays in-group).
        #pragma unroll
        for (int off = 1; off < 16; off <<= 1) {
            vz += __shfl_xor(vz, off, 64);
            nn += __shfl_xor(nn, off, 64);
        }

        const float s = -2.0f * vz / nn;
        float4 o;
        o.x = fmaf(s, v4.x, z4.x);
        o.y = fmaf(s, v4.y, z4.y);
        o.z = fmaf(s, v4.z, z4.z);
        o.w = fmaf(s, v4.w, z4.w);
        reinterpret_cast<float4*>(out + base)[lane4] = o;
    }
}

extern "C" void kernel_launch(void* const* d_in, const int* in_sizes, int n_in,
                              void* d_out, int out_size, void* d_ws, size_t ws_size,
                              hipStream_t stream) {
    const float* v = (const float*)d_in[0];
    const float* z = (const float*)d_in[1];
    float* out = (float*)d_out;
    const int B = in_sizes[0] / 64;  // 1048576

    // Memory-bound: cap grid at ~2048 blocks (256 CU x 8 blocks/CU), grid-stride.
    const int block = 256;                       // 16 rows per block per sweep
    const int total_blocks = (B * 16 + block - 1) / block;
    const int grid = total_blocks < 2048 ? total_blocks : 2048;

    HF_28063316312693_kernel<<<grid, block, 0, stream>>>(v, z, out, B);
}

// Round 2
// 145.102 us; speedup vs baseline: 1.1231x; 1.1231x over previous
//
#include <hip/hip_runtime.h>

// Householder reflection per row: out = z - 2 * v * (v.z) / (v.v)
// B = 1048576 rows, L = 64 fp32 per row.
//
// Layout: 4 lanes per row. Each lane loads 4x float4 of v and 4x float4 of z
// (stride 64B within the row) -> 8 independent 16B loads in flight per thread
// (high MLP), 64B-coalesced segments per instruction. Dot-product reduction
// needs only 2 shuffle steps (xor 1, xor 2) across the 4-lane group.
__global__ void __launch_bounds__(256) HF_28063316312693_kernel(
        const float* __restrict__ v,
        const float* __restrict__ z,
        float* __restrict__ out,
        int B) {
    const int tid = blockIdx.x * blockDim.x + threadIdx.x;
    const int row = tid >> 2;          // 4 lanes per row
    const int l4  = tid & 3;           // float4 slot offset within each 16-float chunk
    if (row >= B) return;

    const size_t base = (size_t)row * 64 + (size_t)l4 * 4;  // float index
    const float4* vp = reinterpret_cast<const float4*>(v + base);
    const float4* zp = reinterpret_cast<const float4*>(z + base);

    // Each chunk step is 16 floats = 4 float4s; this lane takes slot l4 of each.
    float4 v0 = vp[0], v1 = vp[4], v2 = vp[8], v3 = vp[12];
    float4 z0 = zp[0], z1 = zp[4], z2 = zp[8], z3 = zp[12];

    float vz = v0.x * z0.x + v0.y * z0.y + v0.z * z0.z + v0.w * z0.w
             + v1.x * z1.x + v1.y * z1.y + v1.z * z1.z + v1.w * z1.w
             + v2.x * z2.x + v2.y * z2.y + v2.z * z2.z + v2.w * z2.w
             + v3.x * z3.x + v3.y * z3.y + v3.z * z3.z + v3.w * z3.w;
    float nn = v0.x * v0.x + v0.y * v0.y + v0.z * v0.z + v0.w * v0.w
             + v1.x * v1.x + v1.y * v1.y + v1.z * v1.z + v1.w * v1.w
             + v2.x * v2.x + v2.y * v2.y + v2.z * v2.z + v2.w * v2.w
             + v3.x * v3.x + v3.y * v3.y + v3.z * v3.z + v3.w * v3.w;

    // Reduce across the 4-lane group: xor 1, xor 2.
    vz += __shfl_xor(vz, 1, 64);
    nn += __shfl_xor(nn, 1, 64);
    vz += __shfl_xor(vz, 2, 64);
    nn += __shfl_xor(nn, 2, 64);

    const float s = -2.0f * vz / nn;

    float4* op = reinterpret_cast<float4*>(out + base);
    float4 o0, o1, o2, o3;
    o0.x = fmaf(s, v0.x, z0.x); o0.y = fmaf(s, v0.y, z0.y);
    o0.z = fmaf(s, v0.z, z0.z); o0.w = fmaf(s, v0.w, z0.w);
    o1.x = fmaf(s, v1.x, z1.x); o1.y = fmaf(s, v1.y, z1.y);
    o1.z = fmaf(s, v1.z, z1.z); o1.w = fmaf(s, v1.w, z1.w);
    o2.x = fmaf(s, v2.x, z2.x); o2.y = fmaf(s, v2.y, z2.y);
    o2.z = fmaf(s, v2.z, z2.z); o2.w = fmaf(s, v2.w, z2.w);
    o3.x = fmaf(s, v3.x, z3.x); o3.y = fmaf(s, v3.y, z3.y);
    o3.z = fmaf(s, v3.z, z3.z); o3.w = fmaf(s, v3.w, z3.w);
    op[0] = o0; op[4] = o1; op[8] = o2; op[12] = o3;
}

extern "C" void kernel_launch(void* const* d_in, const int* in_sizes, int n_in,
                              void* d_out, int out_size, void* d_ws, size_t ws_size,
                              hipStream_t stream) {
    const float* v = (const float*)d_in[0];
    const float* z = (const float*)d_in[1];
    float* out = (float*)d_out;
    const int B = in_sizes[0] / 64;  // 1048576

    // Flat launch: 4 threads per row, one shot (no grid-stride loop).
    const int block = 256;
    const long long total_threads = (long long)B * 4;
    const int grid = (int)((total_threads + block - 1) / block);  // 16384

    HF_28063316312693_kernel<<<grid, block, 0, stream>>>(v, z, out, B);
}